// Round 1
// baseline (116.065 us; speedup 1.0000x reference)
//
#include <hip/hip_runtime.h>
#include <stdint.h>

#define SEQ 2048
#define BATCH 4
#define EMB 512
#define MTOT (BATCH * SEQ)   // 8192 rows
#define WIN 16
#define WINDOW 33            // 2*WIN+1

typedef uint32_t u32;
typedef unsigned short u16;
typedef __attribute__((ext_vector_type(8))) __bf16 bf16x8;
typedef __attribute__((ext_vector_type(4))) float f32x4;
typedef __attribute__((ext_vector_type(2))) u16 u16x2;
typedef __attribute__((ext_vector_type(4))) u16 u16x4;
typedef __attribute__((ext_vector_type(8))) u16 u16x8;

__device__ __forceinline__ u16 f2bf(float f) {  // RNE f32->bf16
  u32 u = __builtin_bit_cast(u32, f);
  u = (u + 0x7fffu + ((u >> 16) & 1u)) >> 16;
  return (u16)u;
}
__device__ __forceinline__ float bf2f(u16 v) {
  return __builtin_bit_cast(float, (u32)v << 16);
}
__device__ __forceinline__ void gload16(void* lds, const void* g) {
  __builtin_amdgcn_global_load_lds((const __attribute__((address_space(1))) u32*)g,
                                   (__attribute__((address_space(3))) u32*)lds, 16, 0, 0);
}

// ---------------- fp32 -> bf16 cast (n multiple of 4) ----------------
__global__ void cast_kernel(const float* __restrict__ src, u16* __restrict__ dst, int n) {
  int i = (blockIdx.x * blockDim.x + threadIdx.x) * 4;
  if (i >= n) return;
  float4 v = *reinterpret_cast<const float4*>(src + i);
  u16x4 o;
  o.x = f2bf(v.x); o.y = f2bf(v.y); o.z = f2bf(v.z); o.w = f2bf(v.w);
  *reinterpret_cast<u16x4*>(dst + i) = o;
}

// ---------------- A_t[n][k] = sum_d Wk[d][n]*Wq[d][k]  (bf16 out) ----------------
__global__ void atmat_kernel(const float* __restrict__ Wq, const float* __restrict__ Wk,
                             u16* __restrict__ At) {
  __shared__ float Kt[32][33];
  __shared__ float Qt[32][33];
  int t = threadIdx.x;
  int lr = t >> 5, lc = t & 31;
  int k0 = blockIdx.x * 32, n0 = blockIdx.y * 32;
  float acc[4] = {0.f, 0.f, 0.f, 0.f};
  for (int d0 = 0; d0 < EMB; d0 += 32) {
    __syncthreads();
#pragma unroll
    for (int rr = 0; rr < 32; rr += 8) {
      Kt[rr + lr][lc] = Wk[(size_t)(d0 + rr + lr) * EMB + n0 + lc];
      Qt[rr + lr][lc] = Wq[(size_t)(d0 + rr + lr) * EMB + k0 + lc];
    }
    __syncthreads();
#pragma unroll 8
    for (int d = 0; d < 32; ++d) {
      float q = Qt[d][lc];
#pragma unroll
      for (int i = 0; i < 4; ++i) acc[i] += Kt[d][lr * 4 + i] * q;
    }
  }
#pragma unroll
  for (int i = 0; i < 4; ++i)
    At[(size_t)(n0 + lr * 4 + i) * EMB + k0 + lc] = f2bf(acc[i]);
}

// ---------------- cvec[i] = sum_d Wq[d][i]*bk[d] + Wk[d][i]*bq[d]; econst = bq.bk ----------------
__global__ void cvec_kernel(const float* __restrict__ Wq, const float* __restrict__ Wk,
                            const float* __restrict__ bq, const float* __restrict__ bk,
                            float* __restrict__ cvec, float* __restrict__ econst) {
  int t = threadIdx.x;
  if (blockIdx.x == 8) {
    __shared__ float red[256];
    float s = bq[t] * bk[t] + bq[t + 256] * bk[t + 256];
    red[t] = s;
    __syncthreads();
    for (int st = 128; st > 0; st >>= 1) {
      if (t < st) red[t] += red[t + st];
      __syncthreads();
    }
    if (t == 0) *econst = red[0];
    return;
  }
  int ii = t >> 2, di = t & 3;
  int i = blockIdx.x * 64 + ii;
  float s = 0.f;
  for (int d = di * 128; d < di * 128 + 128; ++d)
    s += Wq[(size_t)d * EMB + i] * bk[d] + Wk[(size_t)d * EMB + i] * bq[d];
  __shared__ float red[256];
  red[t] = s;
  __syncthreads();
  if (di == 0) cvec[i] = red[t] + red[t + 1] + red[t + 2] + red[t + 3];
}

// ---------------- bf16 GEMM: C[m,n] = sum_k A[m,k]*B[n,k]  (m97 128x128 structure) ----------------
// MODE 0: outF = C + bias (fp32).  MODE 1: outB = C + bias (bf16).
// MODE 2: e_part[slot][m] = sum_{n in block-cols} (C[m,n]+cvec[n]) * xf[m,n]  (row-dot, no C write)
template <int MODE>
__global__ void __launch_bounds__(256) gemm_bt(
    const u16* __restrict__ A, const u16* __restrict__ B,
    float* __restrict__ outF, u16* __restrict__ outB,
    const float* __restrict__ bias,
    const float* __restrict__ cvec, const float* __restrict__ xf,
    float* __restrict__ e_part) {
  __shared__ u16 At[128 * 32];
  __shared__ u16 Bt[128 * 32];
  int t = threadIdx.x;
  int wave = t >> 6, lane = t & 63;
  int wr = wave >> 1, wc = wave & 1;
  int fr = lane & 15, fq = lane >> 4;
  int m0 = blockIdx.x * 128;
  int n0 = blockIdx.y * 128;
  f32x4 acc[4][4] = {};
  for (int kt = 0; kt < EMB / 32; ++kt) {
    __syncthreads();
    int kb = kt * 32;
#pragma unroll
    for (int it = 0; it < 2; ++it) {
      int chunk = t + it * 256;
      int row = chunk >> 2;
      int col = (chunk & 3) * 8;
      gload16(At + (size_t)(wave * 64 + it * 256) * 8,
              A + (size_t)(m0 + row) * EMB + kb + col);
      gload16(Bt + (size_t)(wave * 64 + it * 256) * 8,
              B + (size_t)(n0 + row) * EMB + kb + col);
    }
    __syncthreads();
    bf16x8 af[4], bfv[4];
#pragma unroll
    for (int m = 0; m < 4; ++m)
      af[m] = *reinterpret_cast<const bf16x8*>(&At[(wr * 64 + m * 16 + fr) * 32 + fq * 8]);
#pragma unroll
    for (int n = 0; n < 4; ++n)
      bfv[n] = *reinterpret_cast<const bf16x8*>(&Bt[(wc * 64 + n * 16 + fr) * 32 + fq * 8]);
#pragma unroll
    for (int m = 0; m < 4; ++m)
#pragma unroll
      for (int n = 0; n < 4; ++n)
        acc[m][n] = __builtin_amdgcn_mfma_f32_16x16x32_bf16(af[m], bfv[n], acc[m][n], 0, 0, 0);
  }
  if (MODE == 2) {
    float cv[4];
#pragma unroll
    for (int n = 0; n < 4; ++n) cv[n] = cvec[n0 + wc * 64 + n * 16 + fr];
#pragma unroll
    for (int m = 0; m < 4; ++m) {
#pragma unroll
      for (int r = 0; r < 4; ++r) {
        int row = m0 + wr * 64 + m * 16 + fq * 4 + r;
        float p = 0.f;
#pragma unroll
        for (int n = 0; n < 4; ++n) {
          int col = n0 + wc * 64 + n * 16 + fr;
          p += (acc[m][n][r] + cv[n]) * xf[(size_t)row * EMB + col];
        }
        p += __shfl_xor(p, 1);
        p += __shfl_xor(p, 2);
        p += __shfl_xor(p, 4);
        p += __shfl_xor(p, 8);
        if (fr == 0) e_part[(size_t)(blockIdx.y * 2 + wc) * MTOT + row] = p;
      }
    }
  } else {
    float bv[4];
#pragma unroll
    for (int n = 0; n < 4; ++n) bv[n] = bias[n0 + wc * 64 + n * 16 + fr];
#pragma unroll
    for (int m = 0; m < 4; ++m)
#pragma unroll
      for (int n = 0; n < 4; ++n) {
        int col = n0 + wc * 64 + n * 16 + fr;
#pragma unroll
        for (int r = 0; r < 4; ++r) {
          int row = m0 + wr * 64 + m * 16 + fq * 4 + r;
          float v = acc[m][n][r] + bv[n];
          if (MODE == 0) outF[(size_t)row * EMB + col] = v;
          else outB[(size_t)row * EMB + col] = f2bf(v);
        }
      }
  }
}

// ---------------- e[m] = sum over 8 partial slots ----------------
__global__ void ereduce_kernel(const float* __restrict__ e_part, float* __restrict__ e) {
  int i = blockIdx.x * 256 + threadIdx.x;
  float s = 0.f;
#pragma unroll
  for (int p = 0; p < 8; ++p) s += e_part[(size_t)p * MTOT + i];
  e[i] = s;
}

// ---------------- sliding-window softmax + weighted V sum -> attn_out (bf16) ----------------
__global__ void __launch_bounds__(256) window_kernel(
    const u16* __restrict__ Vb, const float* __restrict__ e,
    const float* __restrict__ econst_p, const u16* __restrict__ bvb,
    u16* __restrict__ ao) {
  __shared__ u16 Vt[48 * EMB];      // rows s0-16 .. s0+31, bf16, 48 KB
  __shared__ float w[16][WINDOW];
  int t = threadIdx.x;
  int wave = t >> 6;
  int b = blockIdx.y;
  int s0 = blockIdx.x * 16;
  // stage 48 V rows (pad rows come from bvb) — 16B DMA per lane, wave-uniform dest
#pragma unroll
  for (int i = 0; i < 12; ++i) {
    int chunk = t + i * 256;        // 64 chunks per row -> row uniform per wave
    int row = chunk >> 6;
    int c8 = (chunk & 63) * 8;
    int n = s0 + row - WIN;
    const u16* src = (n >= 0 && n < SEQ) ? (Vb + (size_t)(b * SEQ + n) * EMB + c8)
                                         : (bvb + c8);
    gload16(Vt + (size_t)(wave * 64 + i * 256) * 8, src);
  }
  const float scale = 0.044194173824159216f;  // 1/sqrt(512)
  float ec = *econst_p;
  if (t < 16) {
    int sg = s0 + t;
    float ev[WINDOW];
    float mx = -1e30f;
#pragma unroll
    for (int j = 0; j < WINDOW; ++j) {
      int n = sg + j - WIN;
      float raw = (n >= 0 && n < SEQ) ? e[(size_t)b * SEQ + n] : 0.f;
      float sc = scale * (raw + ec);   // pad: raw==0 -> scale*bq.bk, exact
      ev[j] = sc;
      mx = fmaxf(mx, sc);
    }
    float sum = 0.f;
#pragma unroll
    for (int j = 0; j < WINDOW; ++j) { float ex = __expf(ev[j] - mx); ev[j] = ex; sum += ex; }
    float inv = 1.f / sum;
#pragma unroll
    for (int j = 0; j < WINDOW; ++j) w[t][j] = ev[j] * inv;
  }
  __syncthreads();
  // each thread: 8 columns x 4 query rows; read each V row once (b128)
  int cg = t & 63;
  int slg = t >> 6;                  // 0..3 -> sl group of 4
  int d0 = cg * 8;
  float oacc[4][8] = {};
  for (int ri = 0; ri < 36; ++ri) {
    int r = slg * 4 + ri;
    u16x8 v = *reinterpret_cast<const u16x8*>(&Vt[(size_t)r * EMB + d0]);
    float vf[8];
#pragma unroll
    for (int c = 0; c < 8; ++c) vf[c] = bf2f(v[c]);
#pragma unroll
    for (int q = 0; q < 4; ++q) {
      int j = ri - q;                // compile-time per (ri,q)
      if (j >= 0 && j < WINDOW) {
        float wt = w[slg * 4 + q][j];
#pragma unroll
        for (int c = 0; c < 8; ++c) oacc[q][c] += wt * vf[c];
      }
    }
  }
#pragma unroll
  for (int q = 0; q < 4; ++q) {
    u16x8 o;
#pragma unroll
    for (int c = 0; c < 8; ++c) o[c] = f2bf(oacc[q][c]);
    *reinterpret_cast<u16x8*>(&ao[(size_t)(b * SEQ + s0 + slg * 4 + q) * EMB + d0]) = o;
  }
}

extern "C" void kernel_launch(void* const* d_in, const int* in_sizes, int n_in,
                              void* d_out, int out_size, void* d_ws, size_t ws_size,
                              hipStream_t stream) {
  const float* x  = (const float*)d_in[0];
  const float* Wq = (const float*)d_in[1];
  const float* bq = (const float*)d_in[2];
  const float* Wk = (const float*)d_in[3];
  const float* bk = (const float*)d_in[4];
  const float* Wv = (const float*)d_in[5];
  const float* bv = (const float*)d_in[6];
  const float* Wo = (const float*)d_in[7];
  const float* bo = (const float*)d_in[8];
  float* out = (float*)d_out;

  char* ws = (char*)d_ws;
  u16* xb       = (u16*)(ws);                                    // 8 MB (reused as attn_out)
  u16* Vb       = (u16*)(ws + (8u << 20));                       // 8 MB
  u16* Atm      = (u16*)(ws + (16u << 20));                      // 512 KB
  u16* Wvb      = (u16*)(ws + (16u << 20) + (512u << 10));       // 512 KB
  u16* Wob      = (u16*)(ws + (16u << 20) + (1024u << 10));      // 512 KB
  float* e_part = (float*)(ws + (16u << 20) + (1536u << 10));    // 256 KB
  float* e      = (float*)(ws + (16u << 20) + (1792u << 10));    // 32 KB
  float* cvec   = (float*)(ws + (16u << 20) + (1824u << 10));    // 2 KB
  u16* bvb      = (u16*)(ws + (16u << 20) + (1826u << 10));      // 1 KB
  float* econst = (float*)(ws + (16u << 20) + (1827u << 10));    // 4 B

  cast_kernel<<<4096, 256, 0, stream>>>(x, xb, MTOT * EMB);
  cast_kernel<<<256, 256, 0, stream>>>(Wv, Wvb, EMB * EMB);
  cast_kernel<<<256, 256, 0, stream>>>(Wo, Wob, EMB * EMB);
  cast_kernel<<<1, 256, 0, stream>>>(bv, bvb, EMB);
  atmat_kernel<<<dim3(16, 16), 256, 0, stream>>>(Wq, Wk, Atm);
  cvec_kernel<<<9, 256, 0, stream>>>(Wq, Wk, bq, bk, cvec, econst);
  // e partials: T = x@A fused with row-dot against fp32 x
  gemm_bt<2><<<dim3(64, 4), 256, 0, stream>>>(xb, Atm, nullptr, nullptr, nullptr, cvec, x, e_part);
  ereduce_kernel<<<32, 256, 0, stream>>>(e_part, e);
  // V = x@Wv^T + bv  (bf16)
  gemm_bt<1><<<dim3(64, 4), 256, 0, stream>>>(xb, Wvb, nullptr, Vb, bv, nullptr, nullptr, nullptr);
  // window softmax + weighted V -> attn_out (reuses xb)
  window_kernel<<<dim3(SEQ / 16, BATCH), 256, 0, stream>>>(Vb, e, econst, bvb, xb);
  // out = attn_out@Wo^T + bo (fp32)
  gemm_bt<0><<<dim3(64, 4), 256, 0, stream>>>(xb, Wob, out, nullptr, bo, nullptr, nullptr, nullptr);
}

// Round 2
// 85.479 us; speedup vs baseline: 1.3578x; 1.3578x over previous
//
#include <hip/hip_runtime.h>
#include <stdint.h>

#define SEQ 2048
#define BATCH 4
#define EMB 512
#define MTOT (BATCH * SEQ)   // 8192 rows
#define WIN 16
#define WINDOW 33            // 2*WIN+1

typedef uint32_t u32;
typedef unsigned short u16;
typedef __attribute__((ext_vector_type(8))) __bf16 bf16x8;
typedef __attribute__((ext_vector_type(4))) float f32x4;
typedef __attribute__((ext_vector_type(4))) u16 u16x4;
typedef __attribute__((ext_vector_type(8))) u16 u16x8;

__device__ __forceinline__ u16 f2bf(float f) {  // RNE f32->bf16
  u32 u = __builtin_bit_cast(u32, f);
  u = (u + 0x7fffu + ((u >> 16) & 1u)) >> 16;
  return (u16)u;
}
__device__ __forceinline__ float bf2f(u16 v) {
  return __builtin_bit_cast(float, (u32)v << 16);
}
__device__ __forceinline__ void gload16(void* lds, const void* g) {
  __builtin_amdgcn_global_load_lds((const __attribute__((address_space(1))) u32*)g,
                                   (__attribute__((address_space(3))) u32*)lds, 16, 0, 0);
}

// ================= prep: all casts + transposes + cvec + econst (1 launch) ==============
// blocks [0,4096): x cast | [4096,4352): Wq^T cast | [4352,4608): Wk^T cast
// [4608,4864): Wv cast | [4864,5120): Wo cast | [5120,5128): cvec | 5128: econst+bvb
__global__ void __launch_bounds__(256) prep_kernel(
    const float* __restrict__ x, const float* __restrict__ Wq, const float* __restrict__ Wk,
    const float* __restrict__ Wv, const float* __restrict__ Wo,
    const float* __restrict__ bq, const float* __restrict__ bk, const float* __restrict__ bv,
    u16* __restrict__ xb, u16* __restrict__ WqT, u16* __restrict__ WkT,
    u16* __restrict__ Wvb, u16* __restrict__ Wob, u16* __restrict__ bvb,
    float* __restrict__ cvec, float* __restrict__ econst) {
  __shared__ float sh[32 * 33];   // union: transpose tile / reductions
  int bid = blockIdx.x;
  int t = threadIdx.x;
  if (bid < 4096) {                       // ---- x cast, 4 floats/thread
    int i = (bid * 256 + t) * 4;
    float4 v = *reinterpret_cast<const float4*>(x + i);
    u16x4 o; o.x = f2bf(v.x); o.y = f2bf(v.y); o.z = f2bf(v.z); o.w = f2bf(v.w);
    *reinterpret_cast<u16x4*>(xb + i) = o;
  } else if (bid < 4608) {                // ---- transpose-cast Wq / Wk
    bool isQ = bid < 4352;
    int tb = bid - (isQ ? 4096 : 4352);
    const float* S = isQ ? Wq : Wk;
    u16* D = isQ ? WqT : WkT;
    int ti = tb >> 4, tj = tb & 15;       // ti: d-tile (rows), tj: j-tile (cols)
    float (*tile)[33] = reinterpret_cast<float (*)[33]>(sh);
    int lr = t >> 5, lc = t & 31;
#pragma unroll
    for (int rr = 0; rr < 32; rr += 8)
      tile[rr + lr][lc] = S[(size_t)(ti * 32 + rr + lr) * EMB + tj * 32 + lc];
    __syncthreads();
    int jr = t >> 3, dc = (t & 7) * 4;
    u16x4 o;
#pragma unroll
    for (int c = 0; c < 4; ++c) o[c] = f2bf(tile[dc + c][jr]);
    *reinterpret_cast<u16x4*>(D + (size_t)(tj * 32 + jr) * EMB + ti * 32 + dc) = o;
  } else if (bid < 5120) {                // ---- Wv / Wo cast
    bool isV = bid < 4864;
    int cb = bid - (isV ? 4608 : 4864);
    const float* S = isV ? Wv : Wo;
    u16* D = isV ? Wvb : Wob;
    int i = (cb * 256 + t) * 4;
    float4 v = *reinterpret_cast<const float4*>(S + i);
    u16x4 o; o.x = f2bf(v.x); o.y = f2bf(v.y); o.z = f2bf(v.z); o.w = f2bf(v.w);
    *reinterpret_cast<u16x4*>(D + i) = o;
  } else if (bid < 5128) {                // ---- cvec[i] = sum_d Wq[d][i]*bk[d]+Wk[d][i]*bq[d]
    int cb = bid - 5120;
    int ii = t >> 2, di = t & 3;
    int i = cb * 64 + ii;
    float s = 0.f;
    for (int d = di * 128; d < di * 128 + 128; ++d)
      s += Wq[(size_t)d * EMB + i] * bk[d] + Wk[(size_t)d * EMB + i] * bq[d];
    sh[t] = s;
    __syncthreads();
    if (di == 0) cvec[i] = sh[t] + sh[t + 1] + sh[t + 2] + sh[t + 3];
  } else {                                // ---- econst = bq.bk ; bvb cast
    bvb[t] = f2bf(bv[t]);
    bvb[t + 256] = f2bf(bv[t + 256]);
    float s = bq[t] * bk[t] + bq[t + 256] * bk[t + 256];
    sh[t] = s;
    __syncthreads();
    for (int st = 128; st > 0; st >>= 1) {
      if (t < st) sh[t] += sh[t + st];
      __syncthreads();
    }
    if (t == 0) *econst = sh[0];
  }
}

// ================= bf16 GEMM template (m97 128x128): C[m,n] = sum_k A[m,k]*B[n,k] ========
// MODE 0: outF = C + bias (fp32).  MODE 3: outB = C (bf16, no bias).
// 1D grid (multiple of 8), XCD-chunked swizzle; decode by = wg&3, bx = wg>>2.
template <int MODE>
__global__ void __launch_bounds__(256) gemm_bt(
    const u16* __restrict__ A, const u16* __restrict__ Bm,
    float* __restrict__ outF, u16* __restrict__ outB,
    const float* __restrict__ bias) {
  __shared__ u16 At[128 * 32];
  __shared__ u16 Bt[128 * 32];
  int bid = blockIdx.x;
  int cpx = gridDim.x >> 3;
  int wg = (bid & 7) * cpx + (bid >> 3);
  int bx = wg >> 2, by = wg & 3;
  int t = threadIdx.x;
  int wave = t >> 6, lane = t & 63;
  int wr = wave >> 1, wc = wave & 1;
  int fr = lane & 15, fq = lane >> 4;
  int m0 = bx * 128, n0 = by * 128;
  f32x4 acc[4][4] = {};
  for (int kt = 0; kt < EMB / 32; ++kt) {
    __syncthreads();
    int kb = kt * 32;
#pragma unroll
    for (int it = 0; it < 2; ++it) {
      int chunk = t + it * 256;
      int row = chunk >> 2;
      int col = (chunk & 3) * 8;
      gload16(At + (size_t)(wave * 64 + it * 256) * 8, A + (size_t)(m0 + row) * EMB + kb + col);
      gload16(Bt + (size_t)(wave * 64 + it * 256) * 8, Bm + (size_t)(n0 + row) * EMB + kb + col);
    }
    __syncthreads();
    bf16x8 af[4], bfv[4];
#pragma unroll
    for (int m = 0; m < 4; ++m)
      af[m] = *reinterpret_cast<const bf16x8*>(&At[(wr * 64 + m * 16 + fr) * 32 + fq * 8]);
#pragma unroll
    for (int n = 0; n < 4; ++n)
      bfv[n] = *reinterpret_cast<const bf16x8*>(&Bt[(wc * 64 + n * 16 + fr) * 32 + fq * 8]);
#pragma unroll
    for (int m = 0; m < 4; ++m)
#pragma unroll
      for (int n = 0; n < 4; ++n)
        acc[m][n] = __builtin_amdgcn_mfma_f32_16x16x32_bf16(af[m], bfv[n], acc[m][n], 0, 0, 0);
  }
  float bvv[4];
#pragma unroll
  for (int n = 0; n < 4; ++n) bvv[n] = (MODE == 0) ? bias[n0 + wc * 64 + n * 16 + fr] : 0.f;
#pragma unroll
  for (int m = 0; m < 4; ++m)
#pragma unroll
    for (int n = 0; n < 4; ++n) {
      int col = n0 + wc * 64 + n * 16 + fr;
#pragma unroll
      for (int r = 0; r < 4; ++r) {
        int row = m0 + wr * 64 + m * 16 + fq * 4 + r;
        float v = acc[m][n][r] + bvv[n];
        if (MODE == 0) outF[(size_t)row * EMB + col] = v;
        else outB[(size_t)row * EMB + col] = f2bf(v);
      }
    }
}

// ================= merged E+V GEMM: by<4 -> e_part rowdot epilogue, else V+bias ==========
__global__ void __launch_bounds__(256) gemm_ev(
    const u16* __restrict__ xb, const u16* __restrict__ Atm, const u16* __restrict__ Wvb,
    const float* __restrict__ bv, const float* __restrict__ cvec, const float* __restrict__ xf,
    float* __restrict__ e_part, u16* __restrict__ Vb) {
  __shared__ u16 At[128 * 32];
  __shared__ u16 Bt[128 * 32];
  int bid = blockIdx.x;                 // 512 blocks
  int wg = (bid & 7) * 64 + (bid >> 3); // XCD-chunked
  int by = wg & 7, bx = wg >> 3;
  bool isE = by < 4;
  int t = threadIdx.x;
  int wave = t >> 6, lane = t & 63;
  int wr = wave >> 1, wc = wave & 1;
  int fr = lane & 15, fq = lane >> 4;
  int m0 = bx * 128;
  int n0 = (isE ? by : by - 4) * 128;
  const u16* Bm = isE ? Atm : Wvb;
  f32x4 acc[4][4] = {};
  for (int kt = 0; kt < EMB / 32; ++kt) {
    __syncthreads();
    int kb = kt * 32;
#pragma unroll
    for (int it = 0; it < 2; ++it) {
      int chunk = t + it * 256;
      int row = chunk >> 2;
      int col = (chunk & 3) * 8;
      gload16(At + (size_t)(wave * 64 + it * 256) * 8, xb + (size_t)(m0 + row) * EMB + kb + col);
      gload16(Bt + (size_t)(wave * 64 + it * 256) * 8, Bm + (size_t)(n0 + row) * EMB + kb + col);
    }
    __syncthreads();
    bf16x8 af[4], bfv[4];
#pragma unroll
    for (int m = 0; m < 4; ++m)
      af[m] = *reinterpret_cast<const bf16x8*>(&At[(wr * 64 + m * 16 + fr) * 32 + fq * 8]);
#pragma unroll
    for (int n = 0; n < 4; ++n)
      bfv[n] = *reinterpret_cast<const bf16x8*>(&Bt[(wc * 64 + n * 16 + fr) * 32 + fq * 8]);
#pragma unroll
    for (int m = 0; m < 4; ++m)
#pragma unroll
      for (int n = 0; n < 4; ++n)
        acc[m][n] = __builtin_amdgcn_mfma_f32_16x16x32_bf16(af[m], bfv[n], acc[m][n], 0, 0, 0);
  }
  if (isE) {
    float cv[4];
#pragma unroll
    for (int n = 0; n < 4; ++n) cv[n] = cvec[n0 + wc * 64 + n * 16 + fr];
#pragma unroll
    for (int m = 0; m < 4; ++m) {
#pragma unroll
      for (int r = 0; r < 4; ++r) {
        int row = m0 + wr * 64 + m * 16 + fq * 4 + r;
        float p = 0.f;
#pragma unroll
        for (int n = 0; n < 4; ++n) {
          int col = n0 + wc * 64 + n * 16 + fr;
          p += (acc[m][n][r] + cv[n]) * xf[(size_t)row * EMB + col];
        }
        p += __shfl_xor(p, 1);
        p += __shfl_xor(p, 2);
        p += __shfl_xor(p, 4);
        p += __shfl_xor(p, 8);
        if (fr == 0) e_part[(size_t)(by * 2 + wc) * MTOT + row] = p;
      }
    }
  } else {
    float bvv[4];
#pragma unroll
    for (int n = 0; n < 4; ++n) bvv[n] = bv[n0 + wc * 64 + n * 16 + fr];
#pragma unroll
    for (int m = 0; m < 4; ++m)
#pragma unroll
      for (int n = 0; n < 4; ++n) {
        int col = n0 + wc * 64 + n * 16 + fr;
#pragma unroll
        for (int r = 0; r < 4; ++r) {
          int row = m0 + wr * 64 + m * 16 + fq * 4 + r;
          Vb[(size_t)row * EMB + col] = f2bf(acc[m][n][r] + bvv[n]);
        }
      }
  }
}

// ================= window softmax + weighted V sum (sums e_part inline) ==================
__global__ void __launch_bounds__(256) window_kernel(
    const u16* __restrict__ Vb, const float* __restrict__ e_part,
    const float* __restrict__ econst_p, const u16* __restrict__ bvb,
    u16* __restrict__ ao) {
  __shared__ u16 Vt[48 * EMB];      // rows s0-16 .. s0+31, bf16, 48 KB
  __shared__ float eloc[48];
  __shared__ float w[16][WINDOW];
  int t = threadIdx.x;
  int wave = t >> 6;
  int b = blockIdx.y;
  int s0 = blockIdx.x * 16;
  // stage 48 V rows (pad rows come from bvb) — 16B DMA per lane, wave-uniform dest
#pragma unroll
  for (int i = 0; i < 12; ++i) {
    int chunk = t + i * 256;        // 64 chunks per row -> row uniform per wave
    int row = chunk >> 6;
    int c8 = (chunk & 63) * 8;
    int n = s0 + row - WIN;
    const u16* src = (n >= 0 && n < SEQ) ? (Vb + (size_t)(b * SEQ + n) * EMB + c8)
                                         : (bvb + c8);
    gload16(Vt + (size_t)(wave * 64 + i * 256) * 8, src);
  }
  const float scale = 0.044194173824159216f;  // 1/sqrt(512)
  float ec = *econst_p;
  if (t < 48) {                      // scaled scores for positions s0-16 .. s0+31
    int n = s0 + t - WIN;
    float raw = 0.f;
    if (n >= 0 && n < SEQ) {
      size_t idx = (size_t)b * SEQ + n;
#pragma unroll
      for (int p = 0; p < 8; ++p) raw += e_part[(size_t)p * MTOT + idx];
    }
    eloc[t] = scale * (raw + ec);    // pad: raw==0 -> scale*bq.bk, exact
  }
  __syncthreads();
  if (t < 16) {
    float ev[WINDOW];
    float mx = -1e30f;
#pragma unroll
    for (int j = 0; j < WINDOW; ++j) { ev[j] = eloc[t + j]; mx = fmaxf(mx, ev[j]); }
    float sum = 0.f;
#pragma unroll
    for (int j = 0; j < WINDOW; ++j) { float ex = __expf(ev[j] - mx); ev[j] = ex; sum += ex; }
    float inv = 1.f / sum;
#pragma unroll
    for (int j = 0; j < WINDOW; ++j) w[t][j] = ev[j] * inv;
  }
  __syncthreads();
  // each thread: 8 columns x 4 query rows; read each V row once (b128)
  int cg = t & 63;
  int slg = t >> 6;                  // 0..3 -> query group of 4
  int d0 = cg * 8;
  float oacc[4][8] = {};
  for (int ri = 0; ri < 36; ++ri) {
    int r = slg * 4 + ri;
    u16x8 v = *reinterpret_cast<const u16x8*>(&Vt[(size_t)r * EMB + d0]);
    float vf[8];
#pragma unroll
    for (int c = 0; c < 8; ++c) vf[c] = bf2f(v[c]);
#pragma unroll
    for (int q = 0; q < 4; ++q) {
      int j = ri - q;                // compile-time per (ri,q)
      if (j >= 0 && j < WINDOW) {
        float wt = w[slg * 4 + q][j];
#pragma unroll
        for (int c = 0; c < 8; ++c) oacc[q][c] += wt * vf[c];
      }
    }
  }
#pragma unroll
  for (int q = 0; q < 4; ++q) {
    u16x8 o;
#pragma unroll
    for (int c = 0; c < 8; ++c) o[c] = f2bf(oacc[q][c]);
    *reinterpret_cast<u16x8*>(&ao[(size_t)(b * SEQ + s0 + slg * 4 + q) * EMB + d0]) = o;
  }
}

extern "C" void kernel_launch(void* const* d_in, const int* in_sizes, int n_in,
                              void* d_out, int out_size, void* d_ws, size_t ws_size,
                              hipStream_t stream) {
  const float* x  = (const float*)d_in[0];
  const float* Wq = (const float*)d_in[1];
  const float* bq = (const float*)d_in[2];
  const float* Wk = (const float*)d_in[3];
  const float* bk = (const float*)d_in[4];
  const float* Wv = (const float*)d_in[5];
  const float* bv = (const float*)d_in[6];
  const float* Wo = (const float*)d_in[7];
  const float* bo = (const float*)d_in[8];
  float* out = (float*)d_out;

  char* ws = (char*)d_ws;
  u16* xb       = (u16*)(ws);                                    // 8 MB (reused as attn_out)
  u16* Vb       = (u16*)(ws + (8u << 20));                       // 8 MB
  u16* Atm      = (u16*)(ws + (16u << 20));                      // 512 KB
  u16* Wvb      = (u16*)(ws + (16u << 20) + (512u << 10));       // 512 KB
  u16* Wob      = (u16*)(ws + (16u << 20) + (1024u << 10));      // 512 KB
  u16* WqT      = (u16*)(ws + (16u << 20) + (1536u << 10));      // 512 KB
  u16* WkT      = (u16*)(ws + (16u << 20) + (2048u << 10));      // 512 KB
  float* e_part = (float*)(ws + (16u << 20) + (2560u << 10));    // 256 KB
  float* cvec   = (float*)(ws + (16u << 20) + (2816u << 10));    // 2 KB
  u16* bvb      = (u16*)(ws + (16u << 20) + (2818u << 10));      // 1 KB
  float* econst = (float*)(ws + (16u << 20) + (2819u << 10));    // 4 B

  // 1) all casts/transposes + cvec/econst
  prep_kernel<<<5129, 256, 0, stream>>>(x, Wq, Wk, Wv, Wo, bq, bk, bv,
                                        xb, WqT, WkT, Wvb, Wob, bvb, cvec, econst);
  // 2) At[n][k] = sum_d Wk[d][n]*Wq[d][k] = WkT @ WqT^T (MFMA, bf16 out)
  gemm_bt<3><<<16, 256, 0, stream>>>(WkT, WqT, nullptr, Atm, nullptr);
  // 3) merged: e partials (T=x@A fused rowdot vs fp32 x) + V = x@Wv^T + bv
  gemm_ev<<<512, 256, 0, stream>>>(xb, Atm, Wvb, bv, cvec, x, e_part, Vb);
  // 4) window softmax + weighted V -> attn_out (reuses xb)
  window_kernel<<<dim3(SEQ / 16, BATCH), 256, 0, stream>>>(Vb, e_part, econst, bvb, xb);
  // 5) out = attn_out@Wo^T + bo (fp32)
  gemm_bt<0><<<256, 256, 0, stream>>>(xb, Wob, out, nullptr, bo);
}